// Round 2
// baseline (320.252 us; speedup 1.0000x reference)
//
#include <hip/hip_runtime.h>

// Problem constants (fixed by setup_inputs: B=64, C=16, T=32768, fp32)
#define B_BATCH 64
#define C_CH    16
#define T_LEN   32768
#define THREADS 256
#define WAVES   4
#define EPT     16                     // elements per thread per group
#define CHUNK   (64 * EPT)             // 1024 elements per wave-chunk
#define GROUP   (WAVES * CHUNK)        // 4096 elements per group (4 chunks)
#define NGROUP  (T_LEN / GROUP)        // 8 groups per row
#define NROWS   (B_BATCH * C_CH)       // 1024 rows -> 1024 blocks (4/CU)

struct WsLayout { double sum; unsigned int done; unsigned int pad; };

__global__ __launch_bounds__(THREADS) void wloss_kernel(
    const float* __restrict__ pred,
    const float* __restrict__ tru,
    WsLayout* __restrict__ ws,
    float* __restrict__ out)
{
    const int row  = blockIdx.x;           // one block per (b,c) row
    const int tid  = threadIdx.x;
    const int lane = tid & 63;
    const int wave = tid >> 6;             // 4 waves; wave w owns chunk g*4+w

    const float4* p4 = (const float4*)(pred + (size_t)row * T_LEN);
    const float4* t4 = (const float4*)(tru  + (size_t)row * T_LEN);

    __shared__ float wtot[2][WAVES];       // parity-buffered chunk totals

    // thread's float4 base within a group:
    // element base = g*GROUP + wave*CHUNK + lane*EPT  (16 contiguous elems/lane)
    const int tbase4 = wave * (CHUNK / 4) + lane * (EPT / 4);

    float4 pc[4], tc[4], pn[4], tn[4];
    #pragma unroll
    for (int k = 0; k < 4; ++k) {          // preload group 0
        pc[k] = p4[tbase4 + k];
        tc[k] = t4[tbase4 + k];
    }

    float  carry = 0.0f;                   // row-running cumsum at group start
    double acc   = 0.0;                    // per-thread weighted-|cumsum| accum

    for (int g = 0; g < NGROUP; ++g) {
        // ---- prefetch next group while current is processed ----
        if (g + 1 < NGROUP) {
            const int nb = (g + 1) * (GROUP / 4) + tbase4;
            #pragma unroll
            for (int k = 0; k < 4; ++k) {
                pn[k] = p4[nb + k];
                tn[k] = t4[nb + k];
            }
        }

        // ---- local inclusive scan of 16 contiguous diffs ----
        float s[EPT];
        {
            const float* pf = (const float*)pc;
            const float* tf = (const float*)tc;
            float run = 0.0f;
            #pragma unroll
            for (int j = 0; j < EPT; ++j) {
                run += pf[j] - tf[j];
                s[j] = run;
            }
        }

        // ---- wave inclusive scan of per-lane totals (64 lanes) ----
        float v = s[EPT - 1];
        #pragma unroll
        for (int off = 1; off < 64; off <<= 1) {
            float u = __shfl_up(v, off, 64);
            if (lane >= off) v += u;
        }

        // ---- exchange chunk totals across the 4 waves (1 barrier/group) ----
        const int par = g & 1;
        if (lane == 63) wtot[par][wave] = v;   // lane 63's v = chunk total
        __syncthreads();

        float wpre = 0.0f, gtot = 0.0f;
        #pragma unroll
        for (int w = 0; w < WAVES; ++w) {
            float t = wtot[par][w];
            if (w < wave) wpre += t;
            gtot += t;
        }

        // exclusive prefix for this lane's first element (global over row)
        const float excl = carry + wpre + (v - s[EPT - 1]);

        // ---- weighted |cumsum| ----
        const int   e0 = g * GROUP + wave * CHUNK + lane * EPT;
        const float w0 = (float)(T_LEN - e0);
        float part = 0.0f;
        #pragma unroll
        for (int j = 0; j < EPT; ++j)
            part += fabsf(excl + s[j]) * (w0 - (float)j);
        acc += (double)part;                   // fp32 partial (<~1e9) -> double

        carry += gtot;

        #pragma unroll
        for (int k = 0; k < 4; ++k) { pc[k] = pn[k]; tc[k] = tn[k]; }
        // WAR safety: parity buffer + next group's barrier
    }

    // ---- block reduction of double acc ----
    #pragma unroll
    for (int off = 32; off > 0; off >>= 1)
        acc += __shfl_down(acc, off, 64);

    __shared__ double dtot[WAVES];
    if (lane == 0) dtot[wave] = acc;
    __syncthreads();

    if (tid == 0) {
        double sblk = dtot[0] + dtot[1] + dtot[2] + dtot[3];
        atomicAdd(&ws->sum, sblk);             // device-scope f64 atomic
        __threadfence();
        unsigned int prev = atomicAdd(&ws->done, 1u);
        if (prev == NROWS - 1) {               // last block finalizes
            double total = atomicAdd(&ws->sum, 0.0);  // atomic read
            const double tc_     = (double)T_LEN * (double)C_CH;
            const double scaling = 2.0 / (tc_ * (tc_ + 1.0));
            out[0] = (float)(total * scaling / (double)B_BATCH);
        }
    }
}

extern "C" void kernel_launch(void* const* d_in, const int* in_sizes, int n_in,
                              void* d_out, int out_size, void* d_ws, size_t ws_size,
                              hipStream_t stream)
{
    const float* pred = (const float*)d_in[0];
    const float* tru  = (const float*)d_in[1];
    WsLayout*    ws   = (WsLayout*)d_ws;
    float*       out  = (float*)d_out;

    // d_ws is re-poisoned to 0xAA before every launch -> zero accumulator+counter
    hipMemsetAsync(ws, 0, sizeof(WsLayout), stream);

    wloss_kernel<<<NROWS, THREADS, 0, stream>>>(pred, tru, ws, out);
}

// Round 3
// 312.769 us; speedup vs baseline: 1.0239x; 1.0239x over previous
//
#include <hip/hip_runtime.h>

// Problem constants (fixed by setup_inputs: B=64, C=16, T=32768, fp32)
#define B_BATCH 64
#define C_CH    16
#define T_LEN   32768
#define NROWS   (B_BATCH * C_CH)       // 1024 rows, one WAVE per row
#define WSZ     64                     // block = 1 wave, no barriers anywhere
#define CHUNK   256                    // elems per chunk (64 lanes x float4)
#define NCHUNK  (T_LEN / CHUNK)        // 128 chunks per row
#define DEPTH   16                     // prefetch ring depth (chunks in flight)

struct WsLayout { double sum; unsigned int done; unsigned int pad; };

__global__ __launch_bounds__(WSZ, 1) void wloss_kernel(
    const float* __restrict__ pred,
    const float* __restrict__ tru,
    WsLayout* __restrict__ ws,
    float* __restrict__ out)
{
    const int row  = blockIdx.x;
    const int lane = threadIdx.x;      // 0..63, single wave

    const float4* p4 = (const float4*)(pred + (size_t)row * T_LEN);
    const float4* t4 = (const float4*)(tru  + (size_t)row * T_LEN);

    // ---- prefetch ring: DEPTH chunks of (p,t) float4s in registers ----
    float4 pb[DEPTH], tb[DEPTH];
    #pragma unroll
    for (int k = 0; k < DEPTH; ++k) {
        pb[k] = p4[k * 64 + lane];     // coalesced: lanes at 16B stride
        tb[k] = t4[k * 64 + lane];
    }

    float  carry = 0.0f;               // running cumsum at chunk start
    double acc   = 0.0;

    #pragma unroll 1
    for (int base = 0; base < NCHUNK; base += DEPTH) {
        #pragma unroll
        for (int k = 0; k < DEPTH; ++k) {
            const int c = base + k;
            float4 p = pb[k];
            float4 t = tb[k];

            // refill this ring slot from DEPTH chunks ahead (wave-uniform branch)
            const int nc = c + DEPTH;
            if (nc < NCHUNK) {
                pb[k] = p4[nc * 64 + lane];
                tb[k] = t4[nc * 64 + lane];
            }

            // local inclusive scan of 4 diffs
            float d0 = p.x - t.x;
            float d1 = p.y - t.y;
            float d2 = p.z - t.z;
            float d3 = p.w - t.w;
            float s1 = d0;
            float s2 = s1 + d1;
            float s3 = s2 + d2;
            float s4 = s3 + d3;

            // wave inclusive scan of per-lane totals (64 lanes, 6 shuffles)
            float v = s4;
            #pragma unroll
            for (int off = 1; off < 64; off <<= 1) {
                float u = __shfl_up(v, off, 64);
                if (lane >= off) v += u;
            }

            const float excl = carry + (v - s4);   // exclusive prefix, global
            const float ctot = __shfl(v, 63, 64);  // whole-chunk total

            const int   e0 = c * CHUNK + lane * 4;
            const float w0 = (float)(T_LEN - e0);

            float part = fabsf(excl + s1) * w0
                       + fabsf(excl + s2) * (w0 - 1.0f)
                       + fabsf(excl + s3) * (w0 - 2.0f)
                       + fabsf(excl + s4) * (w0 - 3.0f);
            acc += (double)part;       // fp32 chunk partial (<~3e9) -> double

            carry += ctot;             // the only serial cross-chunk dependency
        }
    }

    // ---- wave reduction of double acc ----
    #pragma unroll
    for (int off = 32; off > 0; off >>= 1)
        acc += __shfl_down(acc, off, 64);

    if (lane == 0) {
        atomicAdd(&ws->sum, acc);              // device-scope f64 atomic
        __threadfence();
        unsigned int prev = atomicAdd(&ws->done, 1u);
        if (prev == NROWS - 1) {               // last wave finalizes
            double total = atomicAdd(&ws->sum, 0.0);   // atomic read
            const double tc_     = (double)T_LEN * (double)C_CH;
            const double scaling = 2.0 / (tc_ * (tc_ + 1.0));
            out[0] = (float)(total * scaling / (double)B_BATCH);
        }
    }
}

extern "C" void kernel_launch(void* const* d_in, const int* in_sizes, int n_in,
                              void* d_out, int out_size, void* d_ws, size_t ws_size,
                              hipStream_t stream)
{
    const float* pred = (const float*)d_in[0];
    const float* tru  = (const float*)d_in[1];
    WsLayout*    ws   = (WsLayout*)d_ws;
    float*       out  = (float*)d_out;

    // d_ws re-poisoned to 0xAA before every launch -> zero accumulator+counter
    hipMemsetAsync(ws, 0, sizeof(WsLayout), stream);

    wloss_kernel<<<NROWS, WSZ, 0, stream>>>(pred, tru, ws, out);
}